// Round 1
// baseline (232.141 us; speedup 1.0000x reference)
//
#include <hip/hip_runtime.h>
#include <math.h>

#define B_ROWS 8192
#define C_COLS 4096
#define D_DIM  1024
#define EPSN   1e-12f

typedef float v4f __attribute__((ext_vector_type(4)));
typedef short v8s __attribute__((ext_vector_type(8)));

__device__ __forceinline__ unsigned short bf16_rtn(float x) {
    unsigned int u = __float_as_uint(x);
    u += 0x7fffu + ((u >> 16) & 1u);
    return (unsigned short)(u >> 16);
}

// strict total order (value desc, index asc) == first-occurrence argmax
__device__ __forceinline__ bool better_vi(float v, int i, float V, int I) {
    return (v > V) || (v == V && i < I);
}

// ---------------------------------------------------------------------------
// Kernel 1: wave-per-row normalize + bf16 convert. (R3-proven, unchanged)
// ---------------------------------------------------------------------------
__global__ __launch_bounds__(256) void prep_kernel(
    const float* __restrict__ emb, const float* __restrict__ cen,
    unsigned short* __restrict__ Ah, unsigned short* __restrict__ Bh,
    float* __restrict__ inv_a, float* __restrict__ inv_b)
{
    const int lane = threadIdx.x & 63;
    const int wid  = blockIdx.x * 4 + (threadIdx.x >> 6);
    const float* src; unsigned short* dst; float* invp; int r;
    if (wid < B_ROWS) { src = emb; r = wid;          dst = Ah; invp = inv_a; }
    else              { src = cen; r = wid - B_ROWS; dst = Bh; invp = inv_b; }

    const float* rp = src + (size_t)r * D_DIM;
    float4 v[4];
    float ss = 0.0f;
    #pragma unroll
    for (int j = 0; j < 4; ++j) {
        v[j] = *(const float4*)(rp + (j * 64 + lane) * 4);
        ss += v[j].x * v[j].x + v[j].y * v[j].y + v[j].z * v[j].z + v[j].w * v[j].w;
    }
    #pragma unroll
    for (int off = 1; off < 64; off <<= 1) ss += __shfl_xor(ss, off, 64);

    const float iv = 1.0f / fmaxf(sqrtf(ss), EPSN);
    if (lane == 0) invp[r] = iv;

    unsigned short* dp = dst + (size_t)r * D_DIM;
    #pragma unroll
    for (int j = 0; j < 4; ++j) {
        ushort4 H;
        H.x = bf16_rtn(v[j].x * iv);
        H.y = bf16_rtn(v[j].y * iv);
        H.z = bf16_rtn(v[j].z * iv);
        H.w = bf16_rtn(v[j].w * iv);
        *(ushort4*)(dp + (j * 64 + lane) * 4) = H;
    }
}

// ---------------------------------------------------------------------------
// Kernel 2 (R7): 8-phase-family schedule port of the bf16 MFMA GEMM + fused
// per-row top-2.
//   tile 128x256, BK=64, 8 waves (2M x 4N), per-wave C = 64x64 (acc[4][4],
//   same epilogue as R6). TRIPLE-buffered LDS (3 x 48 KB = 144 KB): loads for
//   tile t+2 are issued during tile t into the buffer tile t-1 just vacated,
//   so the tile-boundary wait is s_waitcnt vmcnt(6) (t+1's 6 loads done,
//   t+2's 6 stay in flight) -- counted vmcnt, never drained to 0 in the loop
//   (T3+T4). Two phases per K-tile, each: {ds_read subtile + 3 prefetch
//   issues -> s_barrier -> lgkmcnt(0) -> setprio(1) 16 MFMA setprio(0) ->
//   s_barrier} (T5). Swizzle, frag geometry and per-acc K-order identical to
//   R6 (granule g lives at phys g^(row&7), 128-B rows) -> 0 bank conflicts,
//   bit-identical accumulation.
// ---------------------------------------------------------------------------
#define GLD16(gp, lp) \
    __builtin_amdgcn_global_load_lds( \
        (const __attribute__((address_space(1))) void*)(gp), \
        (__attribute__((address_space(3))) void*)(lp), 16, 0, 0)

__global__ __launch_bounds__(512, 2) void simmax_kernel(
    const unsigned short* __restrict__ Ahg, const unsigned short* __restrict__ Bhg,
    float* __restrict__ p1v, int* __restrict__ p1i,
    float* __restrict__ p2v, int* __restrict__ p2i)
{
    // 3 buffers x (A 128x64 bf16 | B 256x64 bf16) = 3 x 24576 shorts = 144 KB
    __shared__ unsigned short lds[3 * 24576];

    const int tid    = threadIdx.x;          // 0..511
    const int L      = tid & 63;
    const int w      = tid >> 6;             // 0..7
    const int lane15 = L & 15;
    const int quad   = L >> 4;
    const int wr     = w >> 2;               // 0..1 (M)
    const int wc     = w & 3;                // 0..3 (N)
    const int row0   = blockIdx.x * 128;
    const int c0     = blockIdx.y * 256;

    // staging: per issue a wave fills 8 rows (1024 B); lane L writes row
    // base+(L>>3), phys granule L&7 == logical granule scol (pre-swizzled src)
    const int scol = (tid & 7) ^ ((tid >> 3) & 7);
    const unsigned short* aB = Ahg + (size_t)(row0 + (tid >> 3)) * D_DIM + scol * 8;
    const unsigned short* bB = Bhg + (size_t)(c0   + (tid >> 3)) * D_DIM + scol * 8;
    const int wofs = w * 512;                // shorts: (w*8 rows) * 64

#define STAGE3A(bo, kb) do { \
    GLD16(aB + (kb),           &lds[(bo) + wofs]);          /* A rows   0..63  */ \
    GLD16(aB + 65536 + (kb),   &lds[(bo) + 4096  + wofs]);  /* A rows  64..127 */ \
    GLD16(bB + (kb),           &lds[(bo) + 8192  + wofs]);  /* B rows   0..63  */ \
} while (0)
#define STAGE3B(bo, kb) do { \
    GLD16(bB + 65536 + (kb),   &lds[(bo) + 12288 + wofs]);  /* B rows  64..127 */ \
    GLD16(bB + 131072 + (kb),  &lds[(bo) + 16384 + wofs]);  /* B rows 128..191 */ \
    GLD16(bB + 196608 + (kb),  &lds[(bo) + 20480 + wofs]);  /* B rows 192..255 */ \
} while (0)

    v4f acc[4][4];
    #pragma unroll
    for (int mt = 0; mt < 4; ++mt)
        #pragma unroll
        for (int nt = 0; nt < 4; ++nt) acc[mt][nt] = (v4f)0.0f;

    // fragment geometry: rows * 64 shorts (128-B rows = full bank wrap)
    int rAo[4], rBo[4];
    #pragma unroll
    for (int t = 0; t < 4; ++t) {
        rAo[t] = (wr * 64 + t * 16 + lane15) * 64;
        rBo[t] = 8192 + (wc * 64 + t * 16 + lane15) * 64;
    }
    const int s7  = lane15 & 7;
    const int cq0 = (quad ^ s7) * 8;         // kk=0: logical granules 0..3
    const int cq1 = ((4 + quad) ^ s7) * 8;   // kk=1: logical granules 4..7

    // prologue: stage tiles 0 and 1, wait tile 0 resident (6 younger in flight)
    STAGE3A(0, 0);      STAGE3B(0, 0);
    STAGE3A(24576, 64); STAGE3B(24576, 64);
    asm volatile("s_waitcnt vmcnt(6)" ::: "memory");
    __builtin_amdgcn_s_barrier();

    int bo_c = 0, bo_n = 24576, bo_n2 = 49152;
    for (int t = 0; t < 16; ++t) {
        const bool pf  = (t + 2 < 16);
        const int  kb2 = (t + 2) * 64;

        // ---------------- phase 0: B frags + A frags mt 0..1 ----------------
        v8s fb[4][2], fa[2][2];
        #pragma unroll
        for (int nt = 0; nt < 4; ++nt) {
            fb[nt][0] = *(const v8s*)&lds[bo_c + rBo[nt] + cq0];
            fb[nt][1] = *(const v8s*)&lds[bo_c + rBo[nt] + cq1];
        }
        #pragma unroll
        for (int mt = 0; mt < 2; ++mt) {
            fa[mt][0] = *(const v8s*)&lds[bo_c + rAo[mt] + cq0];
            fa[mt][1] = *(const v8s*)&lds[bo_c + rAo[mt] + cq1];
        }
        if (pf) STAGE3A(bo_n2, kb2);
        __builtin_amdgcn_s_barrier();
        asm volatile("s_waitcnt lgkmcnt(0)" ::: "memory");
        __builtin_amdgcn_sched_barrier(0);
        __builtin_amdgcn_s_setprio(1);
        #pragma unroll
        for (int kk = 0; kk < 2; ++kk)
            #pragma unroll
            for (int mt = 0; mt < 2; ++mt)
                #pragma unroll
                for (int nt = 0; nt < 4; ++nt)
                    acc[mt][nt] = __builtin_amdgcn_mfma_f32_16x16x32_bf16(
                        fa[mt][kk], fb[nt][kk], acc[mt][nt], 0, 0, 0);
        __builtin_amdgcn_s_setprio(0);
        __builtin_amdgcn_s_barrier();

        // ---------------- phase 1: A frags mt 2..3 (fb held) ----------------
        v8s fa2[2][2];
        #pragma unroll
        for (int mt = 0; mt < 2; ++mt) {
            fa2[mt][0] = *(const v8s*)&lds[bo_c + rAo[2 + mt] + cq0];
            fa2[mt][1] = *(const v8s*)&lds[bo_c + rAo[2 + mt] + cq1];
        }
        if (pf) STAGE3B(bo_n2, kb2);
        __builtin_amdgcn_s_barrier();
        asm volatile("s_waitcnt lgkmcnt(0)" ::: "memory");
        __builtin_amdgcn_sched_barrier(0);
        __builtin_amdgcn_s_setprio(1);
        #pragma unroll
        for (int kk = 0; kk < 2; ++kk)
            #pragma unroll
            for (int mt = 0; mt < 2; ++mt)
                #pragma unroll
                for (int nt = 0; nt < 4; ++nt)
                    acc[2 + mt][nt] = __builtin_amdgcn_mfma_f32_16x16x32_bf16(
                        fa2[mt][kk], fb[nt][kk], acc[2 + mt][nt], 0, 0, 0);
        __builtin_amdgcn_s_setprio(0);

        if (t < 15) {
            // counted wait: tile t+1's 6 loads done; tile t+2's 6 stay in flight
            if (pf) asm volatile("s_waitcnt vmcnt(6)" ::: "memory");
            else    asm volatile("s_waitcnt vmcnt(0)" ::: "memory");
            __builtin_amdgcn_s_barrier();
        }
        const int tb = bo_c; bo_c = bo_n; bo_n = bo_n2; bo_n2 = tb;
    }

    // fused top-2 epilogue. C/D layout: col = lane&15, row = quad*4 + reg.
    const int pc = blockIdx.y * 4 + wc;      // 0..63 column chunk id (64 cols)
    #pragma unroll
    for (int mt = 0; mt < 4; ++mt) {
        #pragma unroll
        for (int r = 0; r < 4; ++r) {
            float a1v = acc[mt][0][r];
            int   a1i = c0 + wc * 64 + 0 * 16 + lane15;
            float a2v = -1e30f;
            int   a2i = 0x7fffffff;
            #pragma unroll
            for (int nt = 1; nt < 4; ++nt) {
                float v  = acc[mt][nt][r];
                int   ci = c0 + wc * 64 + nt * 16 + lane15;
                if (better_vi(v, ci, a1v, a1i))      { a2v = a1v; a2i = a1i; a1v = v; a1i = ci; }
                else if (better_vi(v, ci, a2v, a2i)) { a2v = v;   a2i = ci; }
            }
            #pragma unroll
            for (int off = 8; off; off >>= 1) {
                float b1v = __shfl_down(a1v, off, 64); int b1i = __shfl_down(a1i, off, 64);
                float b2v = __shfl_down(a2v, off, 64); int b2i = __shfl_down(a2i, off, 64);
                if (better_vi(b1v, b1i, a1v, a1i)) {
                    if (better_vi(a1v, a1i, b2v, b2i)) { a2v = a1v; a2i = a1i; }
                    else                               { a2v = b2v; a2i = b2i; }
                    a1v = b1v; a1i = b1i;
                } else if (better_vi(b1v, b1i, a2v, a2i)) {
                    a2v = b1v; a2i = b1i;
                }
            }
            if (lane15 == 0) {
                int rg = row0 + wr * 64 + mt * 16 + quad * 4 + r;
                size_t ix = (size_t)rg * 64 + pc;  // [row][chunk] layout
                p1v[ix] = a1v; p1i[ix] = a1i;
                p2v[ix] = a2v; p2i[ix] = a2i;
            }
        }
    }
}

// ---------------------------------------------------------------------------
// Kernel 3: R3/R5-proven finalize (wave per row, 4 rows/block, j-outer MLP
// rescore). Unchanged.
// ---------------------------------------------------------------------------
__global__ __launch_bounds__(256) void finalize_kernel(
    const float* __restrict__ emb, const float* __restrict__ cen,
    const float* __restrict__ inv_a, const float* __restrict__ inv_b,
    const float* __restrict__ p1v, const int* __restrict__ p1i,
    const float* __restrict__ p2v, const int* __restrict__ p2i,
    float* __restrict__ out)
{
    const int lane = threadIdx.x & 63;
    const int row  = blockIdx.x * 4 + (threadIdx.x >> 6);
    const size_t base = (size_t)row * 64 + lane;

    float v[4]; int ix[4];
    v[0] = p1v[base]; ix[0] = p1i[base];
    v[1] = p2v[base]; ix[1] = p2i[base];
    v[2] = -1e30f;    ix[2] = 0x7ffffffe;
    v[3] = -1e30f;    ix[3] = 0x7fffffff;

    #pragma unroll
    for (int off = 1; off < 64; off <<= 1) {
        float ov[4]; int oi[4];
        #pragma unroll
        for (int k = 0; k < 4; ++k) {
            ov[k] = __shfl_xor(v[k],  off, 64);
            oi[k] = __shfl_xor(ix[k], off, 64);
        }
        #pragma unroll
        for (int k = 0; k < 4; ++k) {
            float bv = ov[k]; int bi = oi[k];
            bool b0 = better_vi(bv, bi, v[0], ix[0]);
            bool b1 = better_vi(bv, bi, v[1], ix[1]);
            bool b2 = better_vi(bv, bi, v[2], ix[2]);
            bool b3 = better_vi(bv, bi, v[3], ix[3]);
            float nv3 = b2 ? v[2] : (b3 ? bv : v[3]); int ni3 = b2 ? ix[2] : (b3 ? bi : ix[3]);
            float nv2 = b1 ? v[1] : (b2 ? bv : v[2]); int ni2 = b1 ? ix[1] : (b2 ? bi : ix[2]);
            float nv1 = b0 ? v[0] : (b1 ? bv : v[1]); int ni1 = b0 ? ix[0] : (b1 ? bi : ix[1]);
            float nv0 = b0 ? bv   : v[0];             int ni0 = b0 ? bi    : ix[0];
            v[0] = nv0; ix[0] = ni0; v[1] = nv1; ix[1] = ni1;
            v[2] = nv2; ix[2] = ni2; v[3] = nv3; ix[3] = ni3;
        }
    }

    const float* er = emb + (size_t)row * D_DIM;
    const float* cr0 = cen + (size_t)ix[0] * D_DIM;
    const float* cr1 = cen + (size_t)ix[1] * D_DIM;
    const float* cr2 = cen + (size_t)ix[2] * D_DIM;
    const float* cr3 = cen + (size_t)ix[3] * D_DIM;

    float d[4] = { 0.0f, 0.0f, 0.0f, 0.0f };
    #pragma unroll
    for (int j = 0; j < 4; ++j) {
        int e = (j * 64 + lane) * 4;
        float4 ev = *(const float4*)(er  + e);
        float4 c0 = *(const float4*)(cr0 + e);
        float4 c1 = *(const float4*)(cr1 + e);
        float4 c2 = *(const float4*)(cr2 + e);
        float4 c3 = *(const float4*)(cr3 + e);
        d[0] += ev.x * c0.x + ev.y * c0.y + ev.z * c0.z + ev.w * c0.w;
        d[1] += ev.x * c1.x + ev.y * c1.y + ev.z * c1.z + ev.w * c1.w;
        d[2] += ev.x * c2.x + ev.y * c2.y + ev.z * c2.z + ev.w * c2.w;
        d[3] += ev.x * c3.x + ev.y * c3.y + ev.z * c3.z + ev.w * c3.w;
    }
    #pragma unroll
    for (int off = 1; off < 64; off <<= 1) {
        #pragma unroll
        for (int c = 0; c < 4; ++c) d[c] += __shfl_xor(d[c], off, 64);
    }

    if (lane == 0) {
        const float ia = inv_a[row];
        float m = -1e30f; int ci = 0x7fffffff;
        #pragma unroll
        for (int c = 0; c < 4; ++c) {
            float s = d[c] * ia * inv_b[ix[c]];
            if (better_vi(s, ix[c], m, ci)) { m = s; ci = ix[c]; }
        }
        if (m <= 0.0f) ci = 0;  // all sims clip to 0 -> argmax = 0
        float ms = fminf(fmaxf(m, 0.0f), 1.0f);
        out[row]          = fminf(fmaxf(sqrtf(1.0f - ms), 0.0f), 1.0f);
        out[B_ROWS + row] = (float)ci;
    }
}

// ---------------------------------------------------------------------------
// Workspace (~33 MB): Ah 16MB | Bh 8MB | inv_a 32KB | inv_b 16KB |
//                     p1v/p1i/p2v/p2i 2MB each ([row][chunk] layout)
// ---------------------------------------------------------------------------
extern "C" void kernel_launch(void* const* d_in, const int* in_sizes, int n_in,
                              void* d_out, int out_size, void* d_ws, size_t ws_size,
                              hipStream_t stream)
{
    const float* emb = (const float*)d_in[0];
    const float* cen = (const float*)d_in[1];
    float* out = (float*)d_out;

    unsigned short* Ahp = (unsigned short*)d_ws;
    unsigned short* Bhp = Ahp + (size_t)B_ROWS * D_DIM;
    float* inv_a = (float*)(Bhp + (size_t)C_COLS * D_DIM);
    float* inv_b = inv_a + B_ROWS;
    float* p1v   = inv_b + C_COLS;
    int*   p1i   = (int*)(p1v + (size_t)64 * B_ROWS);
    float* p2v   = (float*)(p1i + (size_t)64 * B_ROWS);
    int*   p2i   = (int*)(p2v + (size_t)64 * B_ROWS);

    prep_kernel<<<(B_ROWS + C_COLS) / 4, 256, 0, stream>>>(emb, cen, Ahp, Bhp, inv_a, inv_b);

    dim3 grid(B_ROWS / 128, C_COLS / 256);
    simmax_kernel<<<grid, 512, 0, stream>>>(Ahp, Bhp, p1v, p1i, p2v, p2i);

    finalize_kernel<<<B_ROWS / 4, 256, 0, stream>>>(emb, cen, inv_a, inv_b,
                                                    p1v, p1i, p2v, p2i, out);
}

// Round 2
// 222.214 us; speedup vs baseline: 1.0447x; 1.0447x over previous
//
#include <hip/hip_runtime.h>
#include <math.h>

#define B_ROWS 8192
#define C_COLS 4096
#define D_DIM  1024
#define EPSN   1e-12f

typedef float v4f __attribute__((ext_vector_type(4)));
typedef short v8s __attribute__((ext_vector_type(8)));

__device__ __forceinline__ unsigned short bf16_rtn(float x) {
    unsigned int u = __float_as_uint(x);
    u += 0x7fffu + ((u >> 16) & 1u);
    return (unsigned short)(u >> 16);
}

// strict total order (value desc, index asc) == first-occurrence argmax
__device__ __forceinline__ bool better_vi(float v, int i, float V, int I) {
    return (v > V) || (v == V && i < I);
}

// ---------------------------------------------------------------------------
// Kernel 1: wave-per-row normalize + bf16 convert. (R3-proven, unchanged)
// ---------------------------------------------------------------------------
__global__ __launch_bounds__(256) void prep_kernel(
    const float* __restrict__ emb, const float* __restrict__ cen,
    unsigned short* __restrict__ Ah, unsigned short* __restrict__ Bh,
    float* __restrict__ inv_a, float* __restrict__ inv_b)
{
    const int lane = threadIdx.x & 63;
    const int wid  = blockIdx.x * 4 + (threadIdx.x >> 6);
    const float* src; unsigned short* dst; float* invp; int r;
    if (wid < B_ROWS) { src = emb; r = wid;          dst = Ah; invp = inv_a; }
    else              { src = cen; r = wid - B_ROWS; dst = Bh; invp = inv_b; }

    const float* rp = src + (size_t)r * D_DIM;
    float4 v[4];
    float ss = 0.0f;
    #pragma unroll
    for (int j = 0; j < 4; ++j) {
        v[j] = *(const float4*)(rp + (j * 64 + lane) * 4);
        ss += v[j].x * v[j].x + v[j].y * v[j].y + v[j].z * v[j].z + v[j].w * v[j].w;
    }
    #pragma unroll
    for (int off = 1; off < 64; off <<= 1) ss += __shfl_xor(ss, off, 64);

    const float iv = 1.0f / fmaxf(sqrtf(ss), EPSN);
    if (lane == 0) invp[r] = iv;

    unsigned short* dp = dst + (size_t)r * D_DIM;
    #pragma unroll
    for (int j = 0; j < 4; ++j) {
        ushort4 H;
        H.x = bf16_rtn(v[j].x * iv);
        H.y = bf16_rtn(v[j].y * iv);
        H.z = bf16_rtn(v[j].z * iv);
        H.w = bf16_rtn(v[j].w * iv);
        *(ushort4*)(dp + (j * 64 + lane) * 4) = H;
    }
}

// ---------------------------------------------------------------------------
// Kernel 2 (R8): m201-geometry 8-phase GEMM + fused per-row top-2.
//   Tile 256x256, BK=64, 8 waves (2M x 4N), per-wave C = 128x64 (acc[8][4]).
//   Double-buffered LDS 2 x (A 256x64 | B 256x64) bf16 = 128 KB.
//   4 phases per K-tile, 16 MFMA each, split by (kk, m-half); fb for each kk
//   read once and held across two phases -> ds_reads 8/8/4/4 per phase.
//   Staging order per tile: [B0 B1 B2 B3 | Alo0 Alo1 | Ahi0 Ahi1], 2 issues
//   per phase; counted waits: vmcnt(4) end-of-P1 (current tile's A-hi done),
//   vmcnt(2) end-of-tile (next tile's B + A-lo done). Never 0 in main loop.
//   Swizzle identical to R6/R7 (granule g at phys g^(row&7), 128-B rows);
//   per-acc K-order kk0->kk1 per tile -> bit-identical accumulation.
// ---------------------------------------------------------------------------
#define GLD16(gp, lp) \
    __builtin_amdgcn_global_load_lds( \
        (const __attribute__((address_space(1))) void*)(gp), \
        (__attribute__((address_space(3))) void*)(lp), 16, 0, 0)

__global__ __launch_bounds__(512, 2) void simmax_kernel(
    const unsigned short* __restrict__ Ahg, const unsigned short* __restrict__ Bhg,
    float* __restrict__ p1v, int* __restrict__ p1i,
    float* __restrict__ p2v, int* __restrict__ p2i)
{
    // buffer = A(256x64) 16384 shorts | B(256x64) 16384 shorts; 2 buffers
    __shared__ unsigned short lds[2 * 32768];

    const int tid    = threadIdx.x;          // 0..511
    const int L      = tid & 63;
    const int w      = tid >> 6;             // 0..7
    const int lane15 = L & 15;
    const int quad   = L >> 4;
    const int wr     = w >> 2;               // 0..1 (M half)
    const int wc     = w & 3;                // 0..3 (N quarter)
    const int row0   = blockIdx.x * 256;
    const int c0     = blockIdx.y * 256;

    // staging: each issue covers 64 rows (8 rows/wave, 1 KB/wave); lane L
    // writes row base+(L>>3), phys granule L&7 <- logical granule scol
    const int scol = (tid & 7) ^ ((tid >> 3) & 7);
    const unsigned short* aB = Ahg + (size_t)(row0 + (tid >> 3)) * D_DIM + scol * 8;
    const unsigned short* bB = Bhg + (size_t)(c0   + (tid >> 3)) * D_DIM + scol * 8;
    const int wofs = w * 512;                // shorts: (w*8 rows) * 64

#define STG(ptr, off, dst) GLD16((ptr) + (off), &lds[(dst) + wofs])
    // per-tile issue order (kb = K offset in shorts):
#define STAGE_P0(bo, kb) do { STG(bB, (kb),            (bo) + 16384); \
                              STG(bB, 65536  + (kb),   (bo) + 20480); } while (0)
#define STAGE_P1(bo, kb) do { STG(bB, 131072 + (kb),   (bo) + 24576); \
                              STG(bB, 196608 + (kb),   (bo) + 28672); } while (0)
#define STAGE_P2(bo, kb) do { STG(aB, (kb),            (bo) + 0);     \
                              STG(aB, 131072 + (kb),   (bo) + 8192);  } while (0)
#define STAGE_P3(bo, kb) do { STG(aB, 65536  + (kb),   (bo) + 4096);  \
                              STG(aB, 196608 + (kb),   (bo) + 12288); } while (0)

    v4f acc[8][4];
    #pragma unroll
    for (int mt = 0; mt < 8; ++mt)
        #pragma unroll
        for (int nt = 0; nt < 4; ++nt) acc[mt][nt] = (v4f)0.0f;

    // fragment geometry: rows * 64 shorts (128-B rows = full bank wrap)
    int rA[4], rB[4];
    #pragma unroll
    for (int t = 0; t < 4; ++t) {
        rA[t] = (wr * 128 + t * 16 + lane15) * 64;           // m-lo; m-hi = +4096
        rB[t] = 16384 + (wc * 64 + t * 16 + lane15) * 64;
    }
    const int s7  = lane15 & 7;
    const int cq0 = (quad ^ s7) * 8;         // kk=0: logical granules 0..3
    const int cq1 = ((4 + quad) ^ s7) * 8;   // kk=1: logical granules 4..7

    // prologue: stage tile 0 (8 issues, same order as loop), wait B+A-lo done
    STAGE_P0(0, 0); STAGE_P1(0, 0); STAGE_P2(0, 0); STAGE_P3(0, 0);
    asm volatile("s_waitcnt vmcnt(2)" ::: "memory");
    __builtin_amdgcn_s_barrier();

    int bo_c = 0, bo_n = 32768;
    for (int t = 0; t < 16; ++t) {
        const bool pf  = (t < 15);
        const int  kb1 = (t + 1) * 64;

        v8s fb0[4], fb1[4], fx[4];

        // -------- P0: kk0 x m-lo --------
        #pragma unroll
        for (int nt = 0; nt < 4; ++nt) fb0[nt] = *(const v8s*)&lds[bo_c + rB[nt] + cq0];
        #pragma unroll
        for (int m = 0; m < 4; ++m)    fx[m]   = *(const v8s*)&lds[bo_c + rA[m] + cq0];
        if (pf) STAGE_P0(bo_n, kb1);
        __builtin_amdgcn_s_barrier();
        asm volatile("s_waitcnt lgkmcnt(0)" ::: "memory");
        __builtin_amdgcn_sched_barrier(0);
        __builtin_amdgcn_s_setprio(1);
        #pragma unroll
        for (int m = 0; m < 4; ++m)
            #pragma unroll
            for (int nt = 0; nt < 4; ++nt)
                acc[m][nt] = __builtin_amdgcn_mfma_f32_16x16x32_bf16(fx[m], fb0[nt], acc[m][nt], 0, 0, 0);
        __builtin_amdgcn_s_setprio(0);
        __builtin_amdgcn_s_barrier();

        // -------- P1: kk1 x m-lo --------
        #pragma unroll
        for (int nt = 0; nt < 4; ++nt) fb1[nt] = *(const v8s*)&lds[bo_c + rB[nt] + cq1];
        #pragma unroll
        for (int m = 0; m < 4; ++m)    fx[m]   = *(const v8s*)&lds[bo_c + rA[m] + cq1];
        if (pf) STAGE_P1(bo_n, kb1);
        __builtin_amdgcn_s_barrier();
        asm volatile("s_waitcnt lgkmcnt(0)" ::: "memory");
        __builtin_amdgcn_sched_barrier(0);
        __builtin_amdgcn_s_setprio(1);
        #pragma unroll
        for (int m = 0; m < 4; ++m)
            #pragma unroll
            for (int nt = 0; nt < 4; ++nt)
                acc[m][nt] = __builtin_amdgcn_mfma_f32_16x16x32_bf16(fx[m], fb1[nt], acc[m][nt], 0, 0, 0);
        __builtin_amdgcn_s_setprio(0);
        // counted wait: current tile's A-hi (2 oldest outstanding) now done
        if (pf) asm volatile("s_waitcnt vmcnt(4)" ::: "memory");
        else    asm volatile("s_waitcnt vmcnt(0)" ::: "memory");
        __builtin_amdgcn_s_barrier();

        // -------- P2: kk0 x m-hi (fb0 held) --------
        #pragma unroll
        for (int m = 0; m < 4; ++m)    fx[m] = *(const v8s*)&lds[bo_c + rA[m] + 4096 + cq0];
        if (pf) STAGE_P2(bo_n, kb1);
        __builtin_amdgcn_s_barrier();
        asm volatile("s_waitcnt lgkmcnt(0)" ::: "memory");
        __builtin_amdgcn_sched_barrier(0);
        __builtin_amdgcn_s_setprio(1);
        #pragma unroll
        for (int m = 0; m < 4; ++m)
            #pragma unroll
            for (int nt = 0; nt < 4; ++nt)
                acc[4 + m][nt] = __builtin_amdgcn_mfma_f32_16x16x32_bf16(fx[m], fb0[nt], acc[4 + m][nt], 0, 0, 0);
        __builtin_amdgcn_s_setprio(0);
        __builtin_amdgcn_s_barrier();

        // -------- P3: kk1 x m-hi (fb1 held) --------
        #pragma unroll
        for (int m = 0; m < 4; ++m)    fx[m] = *(const v8s*)&lds[bo_c + rA[m] + 4096 + cq1];
        if (pf) STAGE_P3(bo_n, kb1);
        __builtin_amdgcn_s_barrier();
        asm volatile("s_waitcnt lgkmcnt(0)" ::: "memory");
        __builtin_amdgcn_sched_barrier(0);
        __builtin_amdgcn_s_setprio(1);
        #pragma unroll
        for (int m = 0; m < 4; ++m)
            #pragma unroll
            for (int nt = 0; nt < 4; ++nt)
                acc[4 + m][nt] = __builtin_amdgcn_mfma_f32_16x16x32_bf16(fx[m], fb1[nt], acc[4 + m][nt], 0, 0, 0);
        __builtin_amdgcn_s_setprio(0);
        if (pf) {
            // counted wait: next tile's B + A-lo (6 oldest) done; A-hi in flight
            asm volatile("s_waitcnt vmcnt(2)" ::: "memory");
            __builtin_amdgcn_s_barrier();
        }
        const int tb = bo_c; bo_c = bo_n; bo_n = tb;
    }

    // fused top-2 epilogue. C/D layout: col = lane&15, row = quad*4 + reg.
    const int pc = blockIdx.y * 4 + wc;      // 0..63 column chunk id (64 cols)
    #pragma unroll
    for (int mt = 0; mt < 8; ++mt) {
        #pragma unroll
        for (int r = 0; r < 4; ++r) {
            float a1v = acc[mt][0][r];
            int   a1i = c0 + wc * 64 + 0 * 16 + lane15;
            float a2v = -1e30f;
            int   a2i = 0x7fffffff;
            #pragma unroll
            for (int nt = 1; nt < 4; ++nt) {
                float v  = acc[mt][nt][r];
                int   ci = c0 + wc * 64 + nt * 16 + lane15;
                if (better_vi(v, ci, a1v, a1i))      { a2v = a1v; a2i = a1i; a1v = v; a1i = ci; }
                else if (better_vi(v, ci, a2v, a2i)) { a2v = v;   a2i = ci; }
            }
            #pragma unroll
            for (int off = 8; off; off >>= 1) {
                float b1v = __shfl_down(a1v, off, 64); int b1i = __shfl_down(a1i, off, 64);
                float b2v = __shfl_down(a2v, off, 64); int b2i = __shfl_down(a2i, off, 64);
                if (better_vi(b1v, b1i, a1v, a1i)) {
                    if (better_vi(a1v, a1i, b2v, b2i)) { a2v = a1v; a2i = a1i; }
                    else                               { a2v = b2v; a2i = b2i; }
                    a1v = b1v; a1i = b1i;
                } else if (better_vi(b1v, b1i, a2v, a2i)) {
                    a2v = b1v; a2i = b1i;
                }
            }
            if (lane15 == 0) {
                int rg = row0 + wr * 128 + mt * 16 + quad * 4 + r;
                size_t ix = (size_t)rg * 64 + pc;  // [row][chunk] layout
                p1v[ix] = a1v; p1i[ix] = a1i;
                p2v[ix] = a2v; p2i[ix] = a2i;
            }
        }
    }
}

// ---------------------------------------------------------------------------
// Kernel 3: R3/R5-proven finalize (wave per row, 4 rows/block, j-outer MLP
// rescore). Unchanged.
// ---------------------------------------------------------------------------
__global__ __launch_bounds__(256) void finalize_kernel(
    const float* __restrict__ emb, const float* __restrict__ cen,
    const float* __restrict__ inv_a, const float* __restrict__ inv_b,
    const float* __restrict__ p1v, const int* __restrict__ p1i,
    const float* __restrict__ p2v, const int* __restrict__ p2i,
    float* __restrict__ out)
{
    const int lane = threadIdx.x & 63;
    const int row  = blockIdx.x * 4 + (threadIdx.x >> 6);
    const size_t base = (size_t)row * 64 + lane;

    float v[4]; int ix[4];
    v[0] = p1v[base]; ix[0] = p1i[base];
    v[1] = p2v[base]; ix[1] = p2i[base];
    v[2] = -1e30f;    ix[2] = 0x7ffffffe;
    v[3] = -1e30f;    ix[3] = 0x7fffffff;

    #pragma unroll
    for (int off = 1; off < 64; off <<= 1) {
        float ov[4]; int oi[4];
        #pragma unroll
        for (int k = 0; k < 4; ++k) {
            ov[k] = __shfl_xor(v[k],  off, 64);
            oi[k] = __shfl_xor(ix[k], off, 64);
        }
        #pragma unroll
        for (int k = 0; k < 4; ++k) {
            float bv = ov[k]; int bi = oi[k];
            bool b0 = better_vi(bv, bi, v[0], ix[0]);
            bool b1 = better_vi(bv, bi, v[1], ix[1]);
            bool b2 = better_vi(bv, bi, v[2], ix[2]);
            bool b3 = better_vi(bv, bi, v[3], ix[3]);
            float nv3 = b2 ? v[2] : (b3 ? bv : v[3]); int ni3 = b2 ? ix[2] : (b3 ? bi : ix[3]);
            float nv2 = b1 ? v[1] : (b2 ? bv : v[2]); int ni2 = b1 ? ix[1] : (b2 ? bi : ix[2]);
            float nv1 = b0 ? v[0] : (b1 ? bv : v[1]); int ni1 = b0 ? ix[0] : (b1 ? bi : ix[1]);
            float nv0 = b0 ? bv   : v[0];             int ni0 = b0 ? bi    : ix[0];
            v[0] = nv0; ix[0] = ni0; v[1] = nv1; ix[1] = ni1;
            v[2] = nv2; ix[2] = ni2; v[3] = nv3; ix[3] = ni3;
        }
    }

    const float* er = emb + (size_t)row * D_DIM;
    const float* cr0 = cen + (size_t)ix[0] * D_DIM;
    const float* cr1 = cen + (size_t)ix[1] * D_DIM;
    const float* cr2 = cen + (size_t)ix[2] * D_DIM;
    const float* cr3 = cen + (size_t)ix[3] * D_DIM;

    float d[4] = { 0.0f, 0.0f, 0.0f, 0.0f };
    #pragma unroll
    for (int j = 0; j < 4; ++j) {
        int e = (j * 64 + lane) * 4;
        float4 ev = *(const float4*)(er  + e);
        float4 c0 = *(const float4*)(cr0 + e);
        float4 c1 = *(const float4*)(cr1 + e);
        float4 c2 = *(const float4*)(cr2 + e);
        float4 c3 = *(const float4*)(cr3 + e);
        d[0] += ev.x * c0.x + ev.y * c0.y + ev.z * c0.z + ev.w * c0.w;
        d[1] += ev.x * c1.x + ev.y * c1.y + ev.z * c1.z + ev.w * c1.w;
        d[2] += ev.x * c2.x + ev.y * c2.y + ev.z * c2.z + ev.w * c2.w;
        d[3] += ev.x * c3.x + ev.y * c3.y + ev.z * c3.z + ev.w * c3.w;
    }
    #pragma unroll
    for (int off = 1; off < 64; off <<= 1) {
        #pragma unroll
        for (int c = 0; c < 4; ++c) d[c] += __shfl_xor(d[c], off, 64);
    }

    if (lane == 0) {
        const float ia = inv_a[row];
        float m = -1e30f; int ci = 0x7fffffff;
        #pragma unroll
        for (int c = 0; c < 4; ++c) {
            float s = d[c] * ia * inv_b[ix[c]];
            if (better_vi(s, ix[c], m, ci)) { m = s; ci = ix[c]; }
        }
        if (m <= 0.0f) ci = 0;  // all sims clip to 0 -> argmax = 0
        float ms = fminf(fmaxf(m, 0.0f), 1.0f);
        out[row]          = fminf(fmaxf(sqrtf(1.0f - ms), 0.0f), 1.0f);
        out[B_ROWS + row] = (float)ci;
    }
}

// ---------------------------------------------------------------------------
// Workspace (~33 MB): Ah 16MB | Bh 8MB | inv_a 32KB | inv_b 16KB |
//                     p1v/p1i/p2v/p2i 2MB each ([row][chunk] layout)
// ---------------------------------------------------------------------------
extern "C" void kernel_launch(void* const* d_in, const int* in_sizes, int n_in,
                              void* d_out, int out_size, void* d_ws, size_t ws_size,
                              hipStream_t stream)
{
    const float* emb = (const float*)d_in[0];
    const float* cen = (const float*)d_in[1];
    float* out = (float*)d_out;

    unsigned short* Ahp = (unsigned short*)d_ws;
    unsigned short* Bhp = Ahp + (size_t)B_ROWS * D_DIM;
    float* inv_a = (float*)(Bhp + (size_t)C_COLS * D_DIM);
    float* inv_b = inv_a + B_ROWS;
    float* p1v   = inv_b + C_COLS;
    int*   p1i   = (int*)(p1v + (size_t)64 * B_ROWS);
    float* p2v   = (float*)(p1i + (size_t)64 * B_ROWS);
    int*   p2i   = (int*)(p2v + (size_t)64 * B_ROWS);

    prep_kernel<<<(B_ROWS + C_COLS) / 4, 256, 0, stream>>>(emb, cen, Ahp, Bhp, inv_a, inv_b);

    dim3 grid(B_ROWS / 256, C_COLS / 256);
    simmax_kernel<<<grid, 512, 0, stream>>>(Ahp, Bhp, p1v, p1i, p2v, p2i);

    finalize_kernel<<<B_ROWS / 4, 256, 0, stream>>>(emb, cen, inv_a, inv_b,
                                                    p1v, p1i, p2v, p2i, out);
}